// Round 15
// baseline (308.638 us; speedup 1.0000x reference)
//
#include <hip/hip_runtime.h>
#include <stdint.h>

#define B_  64
#define H_  32
#define D_  4096
#define KD  128
#define VD  128
#define M_  4095
#define M1_ 4096
#define NCHUNK 32
#define LOG2E 1.44269504088896f

// ---- workspace layout (float offsets) ----
#define WS_P      0ull
#define WS_Q      4456448ull
#define WS_STATS  4718592ull
#define WS_O      4849664ull
#define WS_OPART  5111808ull

#define WAITVL(n) asm volatile("s_waitcnt vmcnt(" #n ") lgkmcnt(0)" ::: "memory")
#define WAITL()  asm volatile("s_waitcnt lgkmcnt(0)" ::: "memory")
#define BAR()    __builtin_amdgcn_s_barrier()

typedef __attribute__((address_space(3))) char lds_char;
typedef const __attribute__((address_space(1))) char glb_char;

#define FMA4(A, W, G) { (A).x += (W)*(G).x; (A).y += (W)*(G).y; \
                        (A).z += (W)*(G).z; (A).w += (W)*(G).w; }

// ---------------- K1a: partial projections (q, k_new, v_new) ----------------
__global__ __launch_bounds__(256) void k_proj_partial(
    const float* __restrict__ x, const float* __restrict__ Wq,
    const float* __restrict__ Wk, const float* __restrict__ Wv,
    float* __restrict__ P) {
  __shared__ float xs[64][260];
  const int dc = blockIdx.x;
  const int hx = blockIdx.y;
  const int t  = threadIdx.x;
  const float* xsrc = x + dc * 256;
  #pragma unroll
  for (int j = 0; j < 16; ++j) {
    int f = t + 256 * j;
    int row = f >> 6, c4 = f & 63;
    *(float4*)&xs[row][c4 * 4] =
        *(const float4*)(xsrc + (size_t)row * D_ + c4 * 4);
  }
  __syncthreads();
  const int bq = t >> 4;
  const int kg = t & 15;
  const int b0 = bq * 4;
  const float* W = (hx < H_) ? (Wq + (size_t)hx * D_ * KD)
                             : ((hx == H_) ? Wk : Wv);
  const float* wp = W + (size_t)(dc * 256) * KD + kg * 8;
  float acc[4][8];
  #pragma unroll
  for (int i = 0; i < 4; ++i)
    #pragma unroll
    for (int j = 0; j < 8; ++j) acc[i][j] = 0.f;
  #pragma unroll 8
  for (int d = 0; d < 256; ++d) {
    float4 w0 = *(const float4*)(wp + (size_t)d * KD);
    float4 w1 = *(const float4*)(wp + (size_t)d * KD + 4);
    float xv[4];
    #pragma unroll
    for (int i = 0; i < 4; ++i) xv[i] = xs[b0 + i][d];
    #pragma unroll
    for (int i = 0; i < 4; ++i) {
      acc[i][0] += xv[i] * w0.x; acc[i][1] += xv[i] * w0.y;
      acc[i][2] += xv[i] * w0.z; acc[i][3] += xv[i] * w0.w;
      acc[i][4] += xv[i] * w1.x; acc[i][5] += xv[i] * w1.y;
      acc[i][6] += xv[i] * w1.z; acc[i][7] += xv[i] * w1.w;
    }
  }
  #pragma unroll
  for (int i = 0; i < 4; ++i) {
    size_t base = ((size_t)(dc * 64 + b0 + i) * 34 + hx) * KD + kg * 8;
    *(float4*)&P[base]     = make_float4(acc[i][0], acc[i][1], acc[i][2], acc[i][3]);
    *(float4*)&P[base + 4] = make_float4(acc[i][4], acc[i][5], acc[i][6], acc[i][7]);
  }
}

// ---------------- K1b: reduce partials -> q, Kc[.,M,:], Vc[.,M,:] ----------
__global__ __launch_bounds__(256) void k_proj_reduce(
    const float* __restrict__ P, float* __restrict__ q,
    float* __restrict__ Kc, float* __restrict__ Vc) {
  int i = blockIdx.x * 256 + threadIdx.x;
  int k = i & 127;
  int hx = (i >> 7) % 34;
  int b = i / (128 * 34);
  float s = 0.f;
  #pragma unroll
  for (int dc = 0; dc < 16; ++dc)
    s += P[(size_t)dc * (64 * 34 * 128) + (size_t)(b * 34 + hx) * 128 + k];
  if (hx < H_)       q[((size_t)b * H_ + hx) * KD + k] = s;
  else if (hx == H_) Kc[((size_t)b * M1_ + M_) * KD + k] = s;
  else               Vc[((size_t)b * M1_ + M_) * VD + k] = s;
}

// ---------------- K2: flash attention, fully per-wave -----------------------
// BOTH K and V phases are per-wave pipelines: wave w owns rows [w*32,w*32+32)
// of the chunk, staged through its private 8KB ring-2 slice with its own
// vmcnt ledger. Barriers: qs-visible, swl-combine, and 3 for the cross-wave
// o reduction = 5 total (was 10). PV computes the full 32h x 128v partial
// per wave (4h x 16v per lane; 5 LDS reads / 64 FMA), reduced pairwise
// through buf at the end.
__global__ __launch_bounds__(256, 3) void k_flash(
    const float* __restrict__ prevK, const float* __restrict__ prevV,
    const float* __restrict__ q, float* __restrict__ Kc, float* __restrict__ Vc,
    float* __restrict__ o_part, float* __restrict__ stats) {
  __shared__ float buf[2][32 * 128];   // 32 KB: 4 per-wave 8KB ring-2 slices
  __shared__ float upool[4608];        // qs (xor-swizzled, 4096fl) -> wl[128][36]
  __shared__ float swl[4 * 64];        // per-wave per-h {max,sum}
  const int chunk = blockIdx.x;
  const int b = blockIdx.y;
  const int t = threadIdx.x;
  const int m0 = chunk * 128;
  const int w = t >> 6, l = t & 63;

  const float* kbase = prevK + (size_t)b * M_ * KD;
  const float* vbase = prevV + (size_t)b * M_ * VD;
  const float* kapp  = Kc + ((size_t)b * M1_ + M_) * KD;
  const float* vapp  = Vc + ((size_t)b * M1_ + M_) * VD;
  float* kc = Kc + (size_t)b * M1_ * KD;
  float* vc = Vc + (size_t)b * M1_ * VD;

  float* kslice = &buf[0][0] + w * 2048;   // ring-2 of 1024-float subtiles
  const int mw = m0 + w * 32;              // wave's first global row

#define WSTAGE(S, srcb, appr)                                                 \
  {                                                                           \
    float* dst_ = kslice + ((S) & 1) * 1024;                                  \
    _Pragma("unroll")                                                         \
    for (int j = 0; j < 4; ++j) {                                             \
      int f4 = j * 64 + l;                                                    \
      int r = f4 >> 5, p = f4 & 31;                                           \
      int m = mw + (S) * 8 + r;                                               \
      int g4 = p ^ r;                                                         \
      const float* gp = (m < M_) ? ((srcb) + (size_t)m * 128 + g4 * 4)        \
                                 : ((appr) + g4 * 4);                         \
      __builtin_amdgcn_global_load_lds(                                       \
          (glb_char*)gp, (lds_char*)(dst_ + j * 256), 16, 0, 0);              \
    }                                                                         \
  }

#define WCOPY(S, dstp)                                                        \
  {                                                                           \
    const float* s_ = kslice + ((S) & 1) * 1024;                              \
    _Pragma("unroll")                                                         \
    for (int jj = 0; jj < 4; ++jj) {                                          \
      int f4 = jj * 64 + l;                                                   \
      int r = f4 >> 5, p = f4 & 31;                                           \
      int g4 = p ^ r;                                                         \
      float4 v = *(const float4*)&s_[f4 * 4];                                 \
      *(float4*)((dstp) + (size_t)(mw + (S) * 8 + r) * 128 + g4 * 4) = v;     \
    }                                                                         \
  }

  // ---- q -> regs; K0,K1 staged; q -> LDS (xor-swizzled stride-128) ----
  const float* qsrc = q + (size_t)b * H_ * KD;
  float4 qv4[4];
  #pragma unroll
  for (int j = 0; j < 4; ++j) {
    int f = j * 256 + t;
    qv4[j] = *(const float4*)(qsrc + (size_t)(f >> 5) * KD + (f & 31) * 4);
  }
  WSTAGE(0, kbase, kapp); WSTAGE(1, kbase, kapp);
  #pragma unroll
  for (int j = 0; j < 4; ++j) {
    int f = j * 256 + t;
    int row = f >> 5, c4 = f & 31;
    *(float4*)&upool[row * 128 + ((c4 ^ ((row >> 1) & 7)) * 4)] = qv4[j];
  }

  const int rp = l & 3, hg = l >> 2, h0 = hg * 2;       // K-phase mapping
  const int qsw = hg & 7;                                // q col swizzle
  const int hi8 = l >> 3, vi8 = l & 7;                   // V-phase mapping
  const int h0v4 = hi8 * 4, vq0 = vi8 * 4;
  const int wrow0 = w * 32;

  float accL0[8], accL1[8];   // [S*2+half]: row = S*8 + rp + 4*half

#define KLOG(S)                                                               \
  {                                                                           \
    const float* lb = kslice + ((S) & 1) * 1024;                              \
    float c00 = 0.f, c01 = 0.f, c10 = 0.f, c11 = 0.f;                         \
    _Pragma("unroll 8")                                                       \
    for (int k4 = 0; k4 < 32; ++k4) {                                         \
      int qp = (k4 ^ qsw) * 4;       /* position k4^qsw holds element k4 */   \
      float4 qa = *(const float4*)&upool[h0 * 128 + qp];                      \
      float4 qb = *(const float4*)&upool[(h0 + 1) * 128 + qp];                \
      float4 k0v = *(const float4*)&lb[(rp * 32 + (k4 ^ rp)) * 4];            \
      float4 k1v = *(const float4*)&lb[((rp + 4) * 32 + (k4 ^ (rp + 4))) * 4];\
      c00 += qa.x*k0v.x + qa.y*k0v.y + qa.z*k0v.z + qa.w*k0v.w;               \
      c01 += qa.x*k1v.x + qa.y*k1v.y + qa.z*k1v.z + qa.w*k1v.w;               \
      c10 += qb.x*k0v.x + qb.y*k0v.y + qb.z*k0v.z + qb.w*k0v.w;               \
      c11 += qb.x*k1v.x + qb.y*k1v.y + qb.z*k1v.z + qb.w*k1v.w;               \
    }                                                                         \
    accL0[(S)*2] = c00; accL0[(S)*2+1] = c01;                                 \
    accL1[(S)*2] = c10; accL1[(S)*2+1] = c11;                                 \
  }

  float4 av[4][4];   // V-phase accumulators: [hh][vq] (4h x 16v per lane)

#define PV4(S)                                                                \
  {                                                                           \
    const float* lb = kslice + ((S) & 1) * 1024;                              \
    _Pragma("unroll")                                                         \
    for (int mm = 0; mm < 8; ++mm) {                                          \
      float4 w4 = *(const float4*)&upool[(wrow0 + (S) * 8 + mm) * 36 + h0v4]; \
      float4 g0 = *(const float4*)&lb[(mm * 32 + ((vq0 + 0) ^ mm)) * 4];      \
      float4 g1 = *(const float4*)&lb[(mm * 32 + ((vq0 + 1) ^ mm)) * 4];      \
      float4 g2 = *(const float4*)&lb[(mm * 32 + ((vq0 + 2) ^ mm)) * 4];      \
      float4 g3 = *(const float4*)&lb[(mm * 32 + ((vq0 + 3) ^ mm)) * 4];      \
      FMA4(av[0][0], w4.x, g0); FMA4(av[0][1], w4.x, g1);                     \
      FMA4(av[0][2], w4.x, g2); FMA4(av[0][3], w4.x, g3);                     \
      FMA4(av[1][0], w4.y, g0); FMA4(av[1][1], w4.y, g1);                     \
      FMA4(av[1][2], w4.y, g2); FMA4(av[1][3], w4.y, g3);                     \
      FMA4(av[2][0], w4.z, g0); FMA4(av[2][1], w4.z, g1);                     \
      FMA4(av[2][2], w4.z, g2); FMA4(av[2][3], w4.z, g3);                     \
      FMA4(av[3][0], w4.w, g0); FMA4(av[3][1], w4.w, g1);                     \
      FMA4(av[3][2], w4.w, g2); FMA4(av[3][3], w4.w, g3);                     \
    }                                                                         \
  }

  WAITL(); BAR();   // qs visible block-wide (K0,K1 in flight, per-wave vmcnt)

  // ---- K phase: per-wave, barrier-free ----
  WAITVL(4);  KLOG(0); WCOPY(0, kc); WSTAGE(2, kbase, kapp);
  WAITVL(8);  KLOG(1); WCOPY(1, kc); WSTAGE(3, kbase, kapp);
  WAITVL(8);  KLOG(2); WCOPY(2, kc);
  WAITVL(4);  KLOG(3); WCOPY(3, kc);

  // ---- per-wave softmax partial (own 32 rows) ----
  float mx0 = -3.402823466e38f, mx1 = -3.402823466e38f;
  #pragma unroll
  for (int j = 0; j < 8; ++j) {
    mx0 = fmaxf(mx0, accL0[j]);
    mx1 = fmaxf(mx1, accL1[j]);
  }
  mx0 = fmaxf(mx0, __shfl_xor(mx0, 1)); mx0 = fmaxf(mx0, __shfl_xor(mx0, 2));
  mx1 = fmaxf(mx1, __shfl_xor(mx1, 1)); mx1 = fmaxf(mx1, __shfl_xor(mx1, 2));
  float s0 = 0.f, s1 = 0.f;
  #pragma unroll
  for (int j = 0; j < 8; ++j) {
    float e0 = exp2f((accL0[j] - mx0) * LOG2E); accL0[j] = e0; s0 += e0;
    float e1 = exp2f((accL1[j] - mx1) * LOG2E); accL1[j] = e1; s1 += e1;
  }
  s0 += __shfl_xor(s0, 1); s0 += __shfl_xor(s0, 2);
  s1 += __shfl_xor(s1, 1); s1 += __shfl_xor(s1, 2);
  if (rp == 0)
    *(float4*)&swl[w * 64 + h0 * 2] = make_float4(mx0, s0, mx1, s1);
  WAITL(); BAR();   // BARRIER1: swl visible; all K reads of buf done

  // ---- combine across waves; write own-rows weights to wl; stage V0,V1 ----
  WSTAGE(0, vbase, vapp);                              // V0 (slot 0)
  float cm0, cs0, cm1, cs1;
  {
    float4 r0 = *(const float4*)&swl[0 * 64 + h0 * 2];
    float4 r1 = *(const float4*)&swl[1 * 64 + h0 * 2];
    float4 r2 = *(const float4*)&swl[2 * 64 + h0 * 2];
    float4 r3 = *(const float4*)&swl[3 * 64 + h0 * 2];
    cm0 = fmaxf(fmaxf(r0.x, r1.x), fmaxf(r2.x, r3.x));
    cm1 = fmaxf(fmaxf(r0.z, r1.z), fmaxf(r2.z, r3.z));
    cs0 = r0.y * exp2f((r0.x - cm0) * LOG2E) + r1.y * exp2f((r1.x - cm0) * LOG2E)
        + r2.y * exp2f((r2.x - cm0) * LOG2E) + r3.y * exp2f((r3.x - cm0) * LOG2E);
    cs1 = r0.w * exp2f((r0.z - cm1) * LOG2E) + r1.w * exp2f((r1.z - cm1) * LOG2E)
        + r2.w * exp2f((r2.z - cm1) * LOG2E) + r3.w * exp2f((r3.z - cm1) * LOG2E);
    float f0 = exp2f((mx0 - cm0) * LOG2E);
    float f1 = exp2f((mx1 - cm1) * LOG2E);
    #pragma unroll
    for (int S = 0; S < 4; ++S)
      #pragma unroll
      for (int half = 0; half < 2; ++half) {
        int m = wrow0 + S * 8 + rp + 4 * half;         // own rows only
        upool[m * 36 + h0]     = accL0[S * 2 + half] * f0;
        upool[m * 36 + h0 + 1] = accL1[S * 2 + half] * f1;
      }
  }
  WSTAGE(1, vbase, vapp);                              // V1 (slot 1)

  // ---- V phase: per-wave, barrier-free (wl own-rows needs no barrier) ----
  #pragma unroll
  for (int hh = 0; hh < 4; ++hh)
    #pragma unroll
    for (int k = 0; k < 4; ++k) av[hh][k] = make_float4(0.f, 0.f, 0.f, 0.f);

  WAITVL(4);  PV4(0); WCOPY(0, vc); WSTAGE(2, vbase, vapp);
  WAITVL(8);  PV4(1); WCOPY(1, vc); WSTAGE(3, vbase, vapp);
  WAITVL(8);  PV4(2); WCOPY(2, vc);
  WAITVL(4);  PV4(3); WCOPY(3, vc);

  // ---- cross-wave o reduction (pairwise through buf) ----
  float* red = &buf[0][0];
  BAR();                                   // all PV reads of buf done
  if ((w & 1) == 0) {
    float* r_ = red + (w >> 1) * 4096;
    #pragma unroll
    for (int i = 0; i < 16; ++i)
      *(float4*)&r_[(l * 16 + (i ^ (l & 15))) * 4] = av[i >> 2][i & 3];
  }
  WAITL(); BAR();
  if (w & 1) {
    const float* r_ = red + (w >> 1) * 4096;
    #pragma unroll
    for (int i = 0; i < 16; ++i) {
      float4 p = *(const float4*)&r_[(l * 16 + (i ^ (l & 15))) * 4];
      av[i >> 2][i & 3].x += p.x; av[i >> 2][i & 3].y += p.y;
      av[i >> 2][i & 3].z += p.z; av[i >> 2][i & 3].w += p.w;
    }
  }
  if (w == 1) {
    #pragma unroll
    for (int i = 0; i < 16; ++i)
      *(float4*)&red[(l * 16 + (i ^ (l & 15))) * 4] = av[i >> 2][i & 3];
  }
  WAITL(); BAR();
  if (w == 3) {
    size_t obase = ((size_t)(chunk * B_ + b) * H_) * VD;
    #pragma unroll
    for (int i = 0; i < 16; ++i) {
      float4 p = *(const float4*)&red[(l * 16 + (i ^ (l & 15))) * 4];
      int hh = i >> 2, k = i & 3;
      float4 s = av[hh][k];
      s.x += p.x; s.y += p.y; s.z += p.z; s.w += p.w;
      *(float4*)&o_part[obase + (size_t)(h0v4 + hh) * VD + vq0 * 4 + k * 4] = s;
    }
  }

  if (w == 0 && rp == 0) {   // chunk stats (identical in all waves)
    size_t sb0 = (((size_t)b * H_ + h0) * NCHUNK + chunk) * 2;
    *(float2*)&stats[sb0] = make_float2(cm0, cs0);
    size_t sb1 = (((size_t)b * H_ + h0 + 1) * NCHUNK + chunk) * 2;
    *(float2*)&stats[sb1] = make_float2(cm1, cs1);
  }
#undef WSTAGE
#undef WCOPY
#undef KLOG
#undef PV4
}

// ---------------- K3: flash combine -> o -----------------------------------
__global__ __launch_bounds__(128) void k_combine(
    const float* __restrict__ o_part, const float* __restrict__ stats,
    float* __restrict__ o) {
  const int bh = blockIdx.x;
  const int t = threadIdx.x;
  __shared__ float st[64];
  if (t < 64) st[t] = stats[(size_t)bh * 64 + t];
  __syncthreads();
  float M = -3.402823466e38f;
  #pragma unroll
  for (int c = 0; c < NCHUNK; ++c) M = fmaxf(M, st[2 * c]);
  float wc[NCHUNK];
  float denom = 0.f;
  #pragma unroll
  for (int c = 0; c < NCHUNK; ++c) {
    float e = exp2f((st[2 * c] - M) * LOG2E);
    wc[c] = e;
    denom += st[2 * c + 1] * e;
  }
  const float inv = 1.0f / denom;
  const int b = bh >> 5, h = bh & 31;
  float acc = 0.f;
  #pragma unroll 4
  for (int c = 0; c < NCHUNK; ++c)
    acc += wc[c] * o_part[((size_t)(c * B_ + b) * H_ + h) * VD + t];
  o[(size_t)bh * VD + t] = acc * inv;
}

// ---------------- K5: partial y = o . Wo -----------------------------------
__global__ __launch_bounds__(256) void k_out_partial(
    const float* __restrict__ o, const float* __restrict__ Wo,
    float* __restrict__ Py) {
  __shared__ float os[64][260];
  const int dc = blockIdx.x;
  const int hvc = blockIdx.y;
  const int t = threadIdx.x;
  #pragma unroll
  for (int j = 0; j < 16; ++j) {
    int f = t + 256 * j;
    int row = f >> 6, c4 = f & 63;
    *(float4*)&os[row][c4 * 4] =
        *(const float4*)(o + (size_t)row * 4096 + hvc * 256 + c4 * 4);
  }
  __syncthreads();
  const int bq = t >> 4, dg = t & 15;
  const int b0 = bq * 4;
  const float* wp = Wo + (size_t)(hvc * 256) * D_ + dc * 128 + dg * 8;
  float acc[4][8];
  #pragma unroll
  for (int i = 0; i < 4; ++i)
    #pragma unroll
    for (int j = 0; j < 8; ++j) acc[i][j] = 0.f;
  #pragma unroll 8
  for (int hv = 0; hv < 256; ++hv) {
    float4 w0 = *(const float4*)(wp + (size_t)hv * D_);
    float4 w1 = *(const float4*)(wp + (size_t)hv * D_ + 4);
    float ov[4];
    #pragma unroll
    for (int i = 0; i < 4; ++i) ov[i] = os[b0 + i][hv];
    #pragma unroll
    for (int i = 0; i < 4; ++i) {
      acc[i][0] += ov[i] * w0.x; acc[i][1] += ov[i] * w0.y;
      acc[i][2] += ov[i] * w0.z; acc[i][3] += ov[i] * w0.w;
      acc[i][4] += ov[i] * w1.x; acc[i][5] += ov[i] * w1.y;
      acc[i][6] += ov[i] * w1.z; acc[i][7] += ov[i] * w1.w;
    }
  }
  #pragma unroll
  for (int i = 0; i < 4; ++i) {
    size_t base = ((size_t)hvc * 64 + b0 + i) * 4096 + dc * 128 + dg * 8;
    *(float4*)&Py[base]     = make_float4(acc[i][0], acc[i][1], acc[i][2], acc[i][3]);
    *(float4*)&Py[base + 4] = make_float4(acc[i][4], acc[i][5], acc[i][6], acc[i][7]);
  }
}

// ---------------- K5b: reduce partial y ------------------------------------
__global__ __launch_bounds__(256) void k_yreduce(
    const float* __restrict__ Py, float* __restrict__ y) {
  int i = blockIdx.x * 256 + threadIdx.x;
  float s = 0.f;
  #pragma unroll
  for (int c = 0; c < 16; ++c) s += Py[(size_t)c * 262144 + i];
  y[i] = s;
}

extern "C" void kernel_launch(void* const* d_in, const int* in_sizes, int n_in,
                              void* d_out, int out_size, void* d_ws, size_t ws_size,
                              hipStream_t stream) {
  const float* x     = (const float*)d_in[0];
  const float* prevK = (const float*)d_in[1];
  const float* prevV = (const float*)d_in[2];
  const float* Wq    = (const float*)d_in[3];
  const float* Wk    = (const float*)d_in[4];
  const float* Wv    = (const float*)d_in[5];
  const float* Wo    = (const float*)d_in[6];

  float* y  = (float*)d_out;
  float* Kc = y + (size_t)B_ * D_;
  float* Vc = Kc + (size_t)B_ * M1_ * KD;

  float* ws     = (float*)d_ws;
  float* P      = ws + WS_P;
  float* q      = ws + WS_Q;
  float* stats  = ws + WS_STATS;
  float* o      = ws + WS_O;
  float* o_part = ws + WS_OPART;

  k_proj_partial<<<dim3(16, 34), 256, 0, stream>>>(x, Wq, Wk, Wv, P);
  k_proj_reduce<<<1088, 256, 0, stream>>>(P, q, Kc, Vc);
  k_flash<<<dim3(32, 64), 256, 0, stream>>>(prevK, prevV, q, Kc, Vc, o_part, stats);
  k_combine<<<2048, 128, 0, stream>>>(o_part, stats, o);
  k_out_partial<<<dim3(32, 16), 256, 0, stream>>>(o, Wo, P);
  k_yreduce<<<1024, 256, 0, stream>>>(P, y);
}